// Round 10
// baseline (110.269 us; speedup 1.0000x reference)
//
#include <hip/hip_runtime.h>
#include <cstddef>
#include <cstdint>

// TemporalConvTranspose2d, R10: band-paired MFMA, double-buffered sub-tile
// pipeline (read stream of sub-tile k+1 overlaps write stream of sub-tile k).
// x: (B, N_BI*D_IN, T) fp32, chan = s*D_IN + din
// W: (D_OUT, D_IN, K_B, K_T) fp32; b: (D_OUT,); out: (B, N_BO*D_OUT, T) fp32
// Band n = 2q+p: sources s_j = q+j+p-1, kb = 2j+p. Outputs n=2k+1, n=2k+2
// share source bands {k,k+1} and B-fragments (A planes differ by parity).
// Block = (bb, k, t-half of 500). Sub-tiles: [t0,t0+252) and [t0+252,t0+500),
// each staged as 256 rows (halo 4) per band into its own 32KB LDS buffer.
// GEMM per n: out[dout,t] = sum_k A[dout,k] B[k,t], k=(j*3+kt)*32+din, K=192.
// MFMA 16x16x32 bf16, fp32 accum. Verified R5/R8/R9 layouts throughout.

typedef __bf16 bf16x8 __attribute__((ext_vector_type(8)));
typedef __bf16 bf16x4 __attribute__((ext_vector_type(4)));
typedef float  f32x4  __attribute__((ext_vector_type(4)));

#define D_IN_ 32
#define D_OUT_ 32
#define N_BI_ 32
#define N_BO_ 64
#define K_B_ 4
#define K_T_ 3
#define T_ 1000
#define B_ 8

#define XRS_ 256                 // rows per sub-band buffer
#define BANDSTR_ (XRS_ * 64)     // 16384 B
#define SUBSTR_ (2 * BANDSTR_)   // 32768 B per sub-tile buffer
#define WT_ELEMS (2 * 6 * 2 * 64 * 8)   // 12288 bf16 = 24576 B

__device__ __forceinline__ int swz(int t) { return (t & 3) ^ ((t >> 2) & 3); }

// A fragments (verified R5 layout): wt[((p*6+ks)*2+mt)*64 + l], 8 bf16 each:
// dout = mt*16 + (l&15), din = (l>>4)*8 + r, (j,kt) = (ks/3, ks%3), kb = 2j+p.
__global__ __launch_bounds__(256)
void wprep(const float* __restrict__ W, __bf16* __restrict__ wt) {
    int idx = blockIdx.x * 256 + threadIdx.x;
    if (idx >= WT_ELEMS) return;
    int r = idx & 7, l = (idx >> 3) & 63, mt = (idx >> 9) & 1, rest = idx >> 10;
    int ks = rest % 6, p = rest / 6;
    int dout = mt * 16 + (l & 15), din = (l >> 4) * 8 + r;
    int j = ks / 3, kt = ks % 3, kb = 2 * j + p;
    wt[idx] = (__bf16)W[((dout * D_IN_ + din) * K_B_ + kb) * K_T_ + kt];
}

__device__ __forceinline__ void stage_load(const float* xb, bool bandok,
                                           int tbase, int g, int it, f32x4 vv[4]) {
    const int tg = tbase + (g + it * 32) * 4;       // quad-aligned
    const bool ok = bandok && (tg >= 0) && (tg < T_);
#pragma unroll
    for (int i = 0; i < 4; ++i)
        vv[i] = ok ? *(const f32x4*)(xb + (size_t)i * T_ + tg)
                   : (f32x4){0.f, 0.f, 0.f, 0.f};
}

__device__ __forceinline__ void stage_write(unsigned char* lbase, int c, int h,
                                            int g, int it, const f32x4 vv[4]) {
#pragma unroll
    for (int e = 0; e < 4; ++e) {
        const int r = (g + it * 32) * 4 + e;        // local row 0..255
        bf16x4 row;
        row[0] = (__bf16)vv[0][e];
        row[1] = (__bf16)vv[1][e];
        row[2] = (__bf16)vv[2][e];
        row[3] = (__bf16)vv[3][e];
        *(bf16x4*)(lbase + r * 64 + ((c ^ swz(r)) << 4) + (h << 3)) = row;
    }
}

// Compute 2 nt-tiles (nth half) of one sub-tile and store them.
__device__ __forceinline__ void compute_half(
    const unsigned char* xls, const bf16x8 afrag[2][6], const float bv[4],
    int wq, int tl, int cch, int nth, int k, int bb, int mt, int rbase,
    int sub, int t0, float* __restrict__ out)
{
#pragma unroll
    for (int n4 = 0; n4 < 2; ++n4) {
        const int nt = nth * 2 + n4;
        const int lcol = wq * 64 + nt * 16 + tl;
        f32x4 acc[2];
#pragma unroll
        for (int p = 0; p < 2; ++p)
#pragma unroll
            for (int r = 0; r < 4; ++r) acc[p][r] = 0.f;

#pragma unroll
        for (int j = 0; j < 2; ++j) {
            const unsigned char* xbnd = xls + j * BANDSTR_;
#pragma unroll
            for (int kt = 0; kt < 3; ++kt) {
                const int lt = (lcol + kt + 2) & (XRS_ - 1);  // wrap only on masked lanes
                const bf16x8 bfrag = *(const bf16x8*)(xbnd + lt * 64
                                                      + ((cch ^ swz(lt)) << 4));
                const int ks = j * 3 + kt;
                acc[0] = __builtin_amdgcn_mfma_f32_16x16x32_bf16(afrag[0][ks], bfrag, acc[0], 0, 0, 0);
                acc[1] = __builtin_amdgcn_mfma_f32_16x16x32_bf16(afrag[1][ks], bfrag, acc[1], 0, 0, 0);
            }
        }
        const int cap = sub ? 248 : 252;
        if (lcol < cap) {
            const int tcol = t0 + sub * 252 + lcol;
#pragma unroll
            for (int p = 0; p < 2; ++p) {
                const int n = 2 * k + 2 - p;       // p=1 -> 2k+1, p=0 -> 2k+2
                if (n < 0 || n >= N_BO_) continue;
                float* opb = out + ((size_t)(bb * N_BO_ + n) * D_OUT_ + mt * 16 + rbase) * T_ + tcol;
#pragma unroll
                for (int r = 0; r < 4; ++r)
                    opb[(size_t)r * T_] = acc[p][r] + bv[r];
            }
        }
    }
}

// 1D grid 528 = 8 bb x 33 kk x 2 th; bb = wgid&7 (XCD grouping).
__global__ __launch_bounds__(512, 4)
void tct_pair(const float* __restrict__ x, const __bf16* __restrict__ wt,
              const float* __restrict__ bias, float* __restrict__ out)
{
    __shared__ unsigned char xl[2 * SUBSTR_];   // 65536 B: [sub][si][256][64B]

    const int wg  = blockIdx.x;
    const int bb  = wg & 7;
    const int rr  = wg >> 3;
    const int kk  = rr >> 1;
    const int th  = rr & 1;
    const int k   = kk - 1;
    const int t0  = th * 500;

    const int tid = threadIdx.x;
    const int l   = tid & 63;
    const int w   = tid >> 6;
    const int mt  = w >> 2;
    const int wq  = w & 3;
    const int tl  = l & 15;
    const int cch = l >> 4;

    // staging role
    const int g  = tid >> 4;
    const int u  = tid & 15;
    const int si = u >> 3;
    const int dg = u & 7;
    const int s  = k + si;
    const bool bandok = (s >= 0) && (s < N_BI_);
    const float* xb = x + ((size_t)(bb * N_BI_ + (bandok ? s : 0)) * D_IN_ + dg * 4) * T_;
    unsigned char* lb0 = xl + si * BANDSTR_;
    unsigned char* lb1 = xl + SUBSTR_ + si * BANDSTR_;
    const int c = dg >> 1, h = dg & 1;

    // ---- sub0 staging: all 8 loads hoisted ----
    f32x4 vv0[4], vv1[4];
    stage_load(xb, bandok, t0 - 4, g, 0, vv0);
    stage_load(xb, bandok, t0 - 4, g, 1, vv1);

    // A fragments (L2-hot, block-uniform)
    bf16x8 afrag[2][6];
    {
        const bf16x8* wp = (const bf16x8*)wt;
#pragma unroll
        for (int p = 0; p < 2; ++p)
#pragma unroll
            for (int ks = 0; ks < 6; ++ks)
                afrag[p][ks] = wp[p * 768 + ks * 128 + mt * 64 + l];
    }
    const int rbase = cch * 4;
    float bv[4];
#pragma unroll
    for (int r = 0; r < 4; ++r) bv[r] = bias[mt * 16 + rbase + r];

    stage_write(lb0, c, h, g, 0, vv0);
    stage_write(lb0, c, h, g, 1, vv1);
    __syncthreads();

    // ---- pipelined: sub1 loads ride under sub0 compute+stores ----
    stage_load(xb, bandok, t0 + 248, g, 0, vv0);
    compute_half(xl, afrag, bv, wq, tl, cch, 0, k, bb, mt, rbase, 0, t0, out);
    stage_write(lb1, c, h, g, 0, vv0);
    stage_load(xb, bandok, t0 + 248, g, 1, vv1);
    compute_half(xl, afrag, bv, wq, tl, cch, 1, k, bb, mt, rbase, 0, t0, out);
    stage_write(lb1, c, h, g, 1, vv1);
    __syncthreads();

    compute_half(xl + SUBSTR_, afrag, bv, wq, tl, cch, 0, k, bb, mt, rbase, 1, t0, out);
    compute_half(xl + SUBSTR_, afrag, bv, wq, tl, cch, 1, k, bb, mt, rbase, 1, t0, out);
}

// ---- fp32 fallback (no ws) ----
__global__ __launch_bounds__(256)
void tct_fallback(const float* __restrict__ x, const float* __restrict__ W,
                  const float* __restrict__ bias, float* __restrict__ out)
{
    const int lane = threadIdx.x & 63;
    const int wav  = __builtin_amdgcn_readfirstlane(threadIdx.x >> 6);
    const int dog  = wav * 8;
    const int n    = blockIdx.y;
    const int bb   = blockIdx.z;
    const int p    = n & 1;
    int t0 = blockIdx.x * 256 + lane * 4;
    const bool act = (t0 < T_);
    if (!act) t0 = T_ - 4;
    float acc[8][4];
#pragma unroll
    for (int i = 0; i < 8; ++i)
#pragma unroll
        for (int u = 0; u < 4; ++u) acc[i][u] = 0.f;
#pragma unroll
    for (int j = 0; j < 2; ++j) {
        const int s = (n + 2 * j + p - 2) >> 1;
        if (s < 0 || s >= N_BI_) continue;
        const int kb = 2 * j + p;
        const float* xband = x + (size_t)(bb * N_BI_ + s) * D_IN_ * T_;
        for (int d_in = 0; d_in < D_IN_; ++d_in) {
            const float* xr = xband + d_in * T_;
            const float4 xc = *(const float4*)(xr + t0);
            float4 xp = make_float4(0.f, 0.f, 0.f, 0.f);
            if (t0 > 0) xp = *(const float4*)(xr + t0 - 4);
            const float xv[6] = {xp.z, xp.w, xc.x, xc.y, xc.z, xc.w};
#pragma unroll
            for (int kt = 0; kt < K_T_; ++kt) {
                float wv[8];
#pragma unroll
                for (int i = 0; i < 8; ++i) {
                    const int widx = __builtin_amdgcn_readfirstlane(
                        (((dog + i) * D_IN_ + d_in) * K_B_ + kb) * K_T_ + kt);
                    wv[i] = W[widx];
                }
#pragma unroll
                for (int i = 0; i < 8; ++i)
#pragma unroll
                    for (int u = 0; u < 4; ++u)
                        acc[i][u] = fmaf(wv[i], xv[u + kt], acc[i][u]);
            }
        }
    }
    if (act) {
        float bvv[8];
#pragma unroll
        for (int i = 0; i < 8; ++i) bvv[i] = bias[dog + i];
        float* op = out + ((size_t)(bb * N_BO_ + n) * D_OUT_ + dog) * T_ + t0;
#pragma unroll
        for (int i = 0; i < 8; ++i) {
            float4 v;
            v.x = acc[i][0] + bvv[i]; v.y = acc[i][1] + bvv[i];
            v.z = acc[i][2] + bvv[i]; v.w = acc[i][3] + bvv[i];
            *(float4*)(op + (size_t)i * T_) = v;
        }
    }
}

extern "C" void kernel_launch(void* const* d_in, const int* in_sizes, int n_in,
                              void* d_out, int out_size, void* d_ws, size_t ws_size,
                              hipStream_t stream) {
    const float* x    = (const float*)d_in[0];
    const float* W    = (const float*)d_in[1];
    const float* bias = (const float*)d_in[2];
    float* out = (float*)d_out;

    if (ws_size >= (size_t)WT_ELEMS * sizeof(__bf16)) {
        __bf16* wt = (__bf16*)d_ws;
        wprep<<<(WT_ELEMS + 255) / 256, 256, 0, stream>>>(W, wt);
        tct_pair<<<dim3(8 * 33 * 2), dim3(512), 0, stream>>>(x, wt, bias, out);
    } else {
        tct_fallback<<<dim3((T_ + 255) / 256, N_BO_, B_), dim3(256), 0, stream>>>(x, W, bias, out);
    }
}

// Round 11
// 105.899 us; speedup vs baseline: 1.0413x; 1.0413x over previous
//
#include <hip/hip_runtime.h>
#include <cstddef>
#include <cstdint>

// TemporalConvTranspose2d, R11: R9 structure + swapped-operand MFMA so the
// accumulator holds 4 consecutive t per lane -> float4 stores (4x fewer
// store uops), scalar per-lane bias.
// x: (B, N_BI*D_IN, T) fp32, chan = s*D_IN + din
// W: (D_OUT, D_IN, K_B, K_T) fp32; b: (D_OUT,); out: (B, N_BO*D_OUT, T) fp32
// Band n = 2q+p: sources s_j = q+j+p-1, kb = 2j+p. Outputs n=2k+1 (p=1) and
// n=2k+2 (p=0) share source bands {k,k+1} and B-fragments.
// Swapped GEMM: D[t][dout] = sum_din x^T[t][din] * W^T[din][dout]:
//   mfma(a = x-frag, b = W-frag) -> C/D col(l&15)=dout, row(cch*4+r)=t.
// Fragment layouts identical to verified R5/R9 (wprep, LDS, swizzle, ds_read
// addressing all byte-identical); only intrinsic arg order + epilogue change.

typedef __bf16 bf16x8 __attribute__((ext_vector_type(8)));
typedef __bf16 bf16x4 __attribute__((ext_vector_type(4)));
typedef float  f32x4  __attribute__((ext_vector_type(4)));

#define D_IN_ 32
#define D_OUT_ 32
#define N_BI_ 32
#define N_BO_ 64
#define K_B_ 4
#define K_T_ 3
#define T_ 1000
#define B_ 8

#define TT_ 500                  // output t per block (2 tiles cover T)
#define XR_ 512                  // staged rows per band: t in [t0-4, t0+508)
#define ROWB_ 64                 // bytes per LDS row (32 din * 2B)
#define WT_ELEMS (2 * 6 * 2 * 64 * 8)   // 12288 bf16 = 24576 B

__device__ __forceinline__ int swz(int t) { return (t & 3) ^ ((t >> 2) & 3); }

// A fragments (verified R5 layout): wt[((p*6+ks)*2+mt)*64 + l], 8 bf16 each:
// dout = mt*16 + (l&15), din = (l>>4)*8 + r, (j,kt) = (ks/3, ks%3), kb = 2j+p.
__global__ __launch_bounds__(256)
void wprep(const float* __restrict__ W, __bf16* __restrict__ wt) {
    int idx = blockIdx.x * 256 + threadIdx.x;
    if (idx >= WT_ELEMS) return;
    int r = idx & 7, l = (idx >> 3) & 63, mt = (idx >> 9) & 1, rest = idx >> 10;
    int ks = rest % 6, p = rest / 6;
    int dout = mt * 16 + (l & 15), din = (l >> 4) * 8 + r;
    int j = ks / 3, kt = ks % 3, kb = 2 * j + p;
    wt[idx] = (__bf16)W[((dout * D_IN_ + din) * K_B_ + kb) * K_T_ + kt];
}

// 1D grid 528 = 8 bb x 33 kk x 2 th. bb = wgid&7 (XCD grouping heuristic).
// Block: stages bands {k, k+1} for t in [t0-4, t0+508); outputs n = 2k+2-p.
// 8 waves: mt = w>>2 (dout half), wq = w&3 (128-t chunk).
__global__ __launch_bounds__(512, 2)
void tct_pair(const float* __restrict__ x, const __bf16* __restrict__ wt,
              const float* __restrict__ bias, float* __restrict__ out)
{
    __shared__ unsigned char xl[2 * XR_ * ROWB_];   // 65536 B

    const int wg  = blockIdx.x;
    const int bb  = wg & 7;
    const int rr  = wg >> 3;          // 0..65
    const int kk  = rr >> 1;          // 0..32
    const int th  = rr & 1;
    const int k   = kk - 1;
    const int t0  = th * TT_;

    const int tid = threadIdx.x;
    const int l   = tid & 63;
    const int w   = tid >> 6;
    const int mt  = w >> 2;
    const int wq  = w & 3;
    const int tl  = l & 15;
    const int cch = l >> 4;

    // ---- stage bands {k, k+1} -> LDS bf16 [si][row][din], R5 swizzle ----
    {
        const int g  = tid >> 4;       // quad-group 0..31
        const int u  = tid & 15;
        const int si = u >> 3;         // band slot 0/1
        const int dg = u & 7;          // din group of 4
        const int s  = k + si;
        const bool bandok = (s >= 0) && (s < N_BI_);
        const float* xb = x + ((size_t)(bb * N_BI_ + (bandok ? s : 0)) * D_IN_ + dg * 4) * T_;
        unsigned char* lbase = xl + si * (XR_ * ROWB_);
        const int c = dg >> 1, h = dg & 1;

        f32x4 vv[4][4];
#pragma unroll
        for (int it = 0; it < 4; ++it) {
            const int tg = t0 - 4 + (g + it * 32) * 4;   // quad-aligned
            const bool ok = bandok && (tg >= 0) && (tg < T_);
#pragma unroll
            for (int i = 0; i < 4; ++i)
                vv[it][i] = ok ? *(const f32x4*)(xb + (size_t)i * T_ + tg)
                               : (f32x4){0.f, 0.f, 0.f, 0.f};
        }
#pragma unroll
        for (int it = 0; it < 4; ++it) {
            const int tq = g + it * 32;
#pragma unroll
            for (int e = 0; e < 4; ++e) {
                const int t = tq * 4 + e;                // local row 0..511
                bf16x4 row;
                row[0] = (__bf16)vv[it][0][e];
                row[1] = (__bf16)vv[it][1][e];
                row[2] = (__bf16)vv[it][2][e];
                row[3] = (__bf16)vv[it][3][e];
                *(bf16x4*)(lbase + t * ROWB_ + ((c ^ swz(t)) << 4) + (h << 3)) = row;
            }
        }
    }

    // ---- W fragments: both parities for this wave's dout half ----
    bf16x8 afrag[2][6];
    {
        const bf16x8* wp = (const bf16x8*)wt;
#pragma unroll
        for (int p = 0; p < 2; ++p)
#pragma unroll
            for (int ks = 0; ks < 6; ++ks)
                afrag[p][ks] = wp[p * 768 + ks * 128 + mt * 64 + l];
    }

    const int dout = mt * 16 + tl;        // this lane's output row
    const float bvs = bias[dout];

    __syncthreads();

    // ---- main loop: 2 chunks x 4 nt x 6 (j,kt); 1 ds_read feeds 2 MFMAs.
    // Swapped operands: D[t][dout]; acc regs = 4 consecutive t.
#pragma unroll
    for (int ntc = 0; ntc < 2; ++ntc) {
        f32x4 acc[2][4];
#pragma unroll
        for (int p = 0; p < 2; ++p)
#pragma unroll
            for (int n4 = 0; n4 < 4; ++n4)
#pragma unroll
                for (int r = 0; r < 4; ++r) acc[p][n4][r] = 0.f;

#pragma unroll
        for (int n4 = 0; n4 < 4; ++n4) {
            const int nt = ntc * 4 + n4;
#pragma unroll
            for (int j = 0; j < 2; ++j) {
                const unsigned char* xbnd = xl + j * (XR_ * ROWB_);
#pragma unroll
                for (int kt = 0; kt < 3; ++kt) {
                    // x-frag (A-operand): lane l -> x[t = base + (l&15) + kt - 2][din chunk cch]
                    const int lt = (wq * 128 + nt * 16 + tl + kt + 2) & (XR_ - 1);
                    const bf16x8 xfrag = *(const bf16x8*)(xbnd + lt * ROWB_
                                                          + ((cch ^ swz(lt)) << 4));
                    const int ks = j * 3 + kt;
                    acc[0][n4] = __builtin_amdgcn_mfma_f32_16x16x32_bf16(xfrag, afrag[0][ks], acc[0][n4], 0, 0, 0);
                    acc[1][n4] = __builtin_amdgcn_mfma_f32_16x16x32_bf16(xfrag, afrag[1][ks], acc[1][n4], 0, 0, 0);
                }
            }
        }

        // ---- epilogue: lane l -> dout fixed; regs = t quad -> float4 store ----
#pragma unroll
        for (int p = 0; p < 2; ++p) {
            const int n = 2 * k + 2 - p;       // p=1 -> 2k+1, p=0 -> 2k+2
            if (n < 0 || n >= N_BO_) continue;
            float* opb = out + ((size_t)(bb * N_BO_ + n) * D_OUT_ + dout) * T_;
#pragma unroll
            for (int n4 = 0; n4 < 4; ++n4) {
                const int lcol = wq * 128 + (ntc * 4 + n4) * 16 + cch * 4;
                if (lcol < TT_) {              // quad-aligned; t0+lcol+3 <= 999
                    f32x4 v = acc[p][n4];
                    v[0] += bvs; v[1] += bvs; v[2] += bvs; v[3] += bvs;
                    *(f32x4*)(opb + t0 + lcol) = v;
                }
            }
        }
    }
}

// ---- fp32 fallback (no ws) ----
__global__ __launch_bounds__(256)
void tct_fallback(const float* __restrict__ x, const float* __restrict__ W,
                  const float* __restrict__ bias, float* __restrict__ out)
{
    const int lane = threadIdx.x & 63;
    const int wav  = __builtin_amdgcn_readfirstlane(threadIdx.x >> 6);
    const int dog  = wav * 8;
    const int n    = blockIdx.y;
    const int bb   = blockIdx.z;
    const int p    = n & 1;
    int t0 = blockIdx.x * 256 + lane * 4;
    const bool act = (t0 < T_);
    if (!act) t0 = T_ - 4;
    float acc[8][4];
#pragma unroll
    for (int i = 0; i < 8; ++i)
#pragma unroll
        for (int u = 0; u < 4; ++u) acc[i][u] = 0.f;
#pragma unroll
    for (int j = 0; j < 2; ++j) {
        const int s = (n + 2 * j + p - 2) >> 1;
        if (s < 0 || s >= N_BI_) continue;
        const int kb = 2 * j + p;
        const float* xband = x + (size_t)(bb * N_BI_ + s) * D_IN_ * T_;
        for (int d_in = 0; d_in < D_IN_; ++d_in) {
            const float* xr = xband + d_in * T_;
            const float4 xc = *(const float4*)(xr + t0);
            float4 xp = make_float4(0.f, 0.f, 0.f, 0.f);
            if (t0 > 0) xp = *(const float4*)(xr + t0 - 4);
            const float xv[6] = {xp.z, xp.w, xc.x, xc.y, xc.z, xc.w};
#pragma unroll
            for (int kt = 0; kt < K_T_; ++kt) {
                float wv[8];
#pragma unroll
                for (int i = 0; i < 8; ++i) {
                    const int widx = __builtin_amdgcn_readfirstlane(
                        (((dog + i) * D_IN_ + d_in) * K_B_ + kb) * K_T_ + kt);
                    wv[i] = W[widx];
                }
#pragma unroll
                for (int i = 0; i < 8; ++i)
#pragma unroll
                    for (int u = 0; u < 4; ++u)
                        acc[i][u] = fmaf(wv[i], xv[u + kt], acc[i][u]);
            }
        }
    }
    if (act) {
        float bvv[8];
#pragma unroll
        for (int i = 0; i < 8; ++i) bvv[i] = bias[dog + i];
        float* op = out + ((size_t)(bb * N_BO_ + n) * D_OUT_ + dog) * T_ + t0;
#pragma unroll
        for (int i = 0; i < 8; ++i) {
            float4 v;
            v.x = acc[i][0] + bvv[i]; v.y = acc[i][1] + bvv[i];
            v.z = acc[i][2] + bvv[i]; v.w = acc[i][3] + bvv[i];
            *(float4*)(op + (size_t)i * T_) = v;
        }
    }
}

extern "C" void kernel_launch(void* const* d_in, const int* in_sizes, int n_in,
                              void* d_out, int out_size, void* d_ws, size_t ws_size,
                              hipStream_t stream) {
    const float* x    = (const float*)d_in[0];
    const float* W    = (const float*)d_in[1];
    const float* bias = (const float*)d_in[2];
    float* out = (float*)d_out;

    if (ws_size >= (size_t)WT_ELEMS * sizeof(__bf16)) {
        __bf16* wt = (__bf16*)d_ws;
        wprep<<<(WT_ELEMS + 255) / 256, 256, 0, stream>>>(W, wt);
        tct_pair<<<dim3(8 * 33 * 2), dim3(512), 0, stream>>>(x, wt, bias, out);
    } else {
        tct_fallback<<<dim3((T_ + 255) / 256, N_BO_, B_), dim3(256), 0, stream>>>(x, W, bias, out);
    }
}